// Round 2
// baseline (9448.867 us; speedup 1.0000x reference)
//
#include <hip/hip_runtime.h>
#include <stdint.h>

typedef float f32x2 __attribute__((ext_vector_type(2)));
typedef unsigned int u32;

#define B_ 256
#define T_ 256
#define I_ 128
#define H_ 512
#define O_ 128
#define CH 16     // timestep chunk held in workspace
#define K1R 32    // rows per k1 block
#define K1P 34    // LDS leading pad (even => 8B-aligned f32x2 rows; 2-way bank alias is free)

__device__ __forceinline__ f32x2 bf2f(u32 u) {
    f32x2 r;
    r.x = __uint_as_float(u << 16);
    r.y = __uint_as_float(u & 0xffff0000u);
    return r;
}
__device__ __forceinline__ u32 packbf(f32x2 v) {
    u32 a = __float_as_uint(v.x); a += 0x7fffu + ((a >> 16) & 1u);
    u32 b = __float_as_uint(v.y); b += 0x7fffu + ((b >> 16) & 1u);
    return (a >> 16) | (b & 0xffff0000u);
}
__device__ __forceinline__ f32x2 sigv(f32x2 x) {
    f32x2 r;
    r.x = 1.f / (1.f + __expf(-x.x));
    r.y = 1.f / (1.f + __expf(-x.y));
    return r;
}
__device__ __forceinline__ f32x2 tanhv(f32x2 x) {
    f32x2 r;
    r.x = 1.f - 2.f / (__expf(2.f * x.x) + 1.f);
    r.y = 1.f - 2.f / (__expf(2.f * x.y) + 1.f);
    return r;
}

// ---------------------------------------------------------------------------
// K0: cast Uz/Ur/Uc (fp32 [H,H]) to packed bf16 pairs: Ub[a][k*256+c] =
// pack(U[k][2c], U[k][2c+1]). Halves k2's L2 weight traffic.
// ---------------------------------------------------------------------------
__global__ __launch_bounds__(256) void k_castU(
    const float* __restrict__ Uz, const float* __restrict__ Ur,
    const float* __restrict__ Uc, u32* __restrict__ Ub)
{
    int t = blockIdx.x * 256 + threadIdx.x;          // < 3*512*256
    int a = t / (H_ * 256);
    int r = t - a * (H_ * 256);
    const float* src = (a == 0) ? Uz : ((a == 1) ? Ur : Uc);
    f32x2 v = ((const f32x2*)src)[r];
    Ub[t] = packbf(v);
}

// ---------------------------------------------------------------------------
// K1: per-gate blocks. blockIdx.x & 3 selects {z, r, c, gamma}; each block
// computes K1R=32 rows of one pre-activation for the current chunk.
// pz/pr/pc = xe@W + (1-m)@V + b   (fp32, layout [tl][b][H])
// gm       = exp(-relu(m@Wgh + bgh))
// ---------------------------------------------------------------------------
__global__ __launch_bounds__(256) void k1_pre(
    const float* __restrict__ x, const float* __restrict__ dl,
    const float* __restrict__ m, const float* __restrict__ xf,
    const float* __restrict__ Wz, const float* __restrict__ Vz, const float* __restrict__ bz,
    const float* __restrict__ Wr, const float* __restrict__ Vr, const float* __restrict__ br,
    const float* __restrict__ Wc, const float* __restrict__ Vc, const float* __restrict__ bc,
    const float* __restrict__ Wgx, const float* __restrict__ Bgx,
    const float* __restrict__ Wgh, const float* __restrict__ Bgh,
    float* __restrict__ pz, float* __restrict__ pr, float* __restrict__ pc,
    float* __restrict__ gm, int t0)
{
    __shared__ float sA[I_ * K1P];   // xe (gates) or m (gamma), layout [k][row]
    __shared__ float sB[I_ * K1P];   // 1-m (gates only)
    const int tid = threadIdx.x;
    const int g = blockIdx.x & 3;
    const int lr0 = (blockIdx.x >> 2) * K1R;      // row base in [0, B_*CH)

    for (int e = tid; e < K1R * I_; e += 256) {
        int rr = e >> 7, k = e & 127;
        int lr = lr0 + rr;
        int b = lr >> 4, tl = lr & 15;            // CH=16
        int gi = (b * T_ + t0 + tl) * I_ + k;
        float mv = m[gi];
        if (g == 3) {
            sA[k * K1P + rr] = mv;
        } else {
            float xv = x[gi], dv = dl[gi], fv = xf[gi];
            float dx = dv * Wgx[k] + Bgx[k];
            float xr = dx * fv + (1.f - dx) * 0.001f;
            sA[k * K1P + rr] = (mv > 0.5f) ? xr : xv;
            sB[k * K1P + rr] = 1.f - mv;
        }
    }
    __syncthreads();

    if (g < 3) {
        const f32x2* W2 = (const f32x2*)((g == 0) ? Wz : (g == 1) ? Wr : Wc);
        const f32x2* V2 = (const f32x2*)((g == 0) ? Vz : (g == 1) ? Vr : Vc);
        const f32x2* bp = (const f32x2*)((g == 0) ? bz : (g == 1) ? br : bc);
        float* dst = (g == 0) ? pz : (g == 1) ? pr : pc;

        f32x2 acc[K1R];
        f32x2 bv = bp[tid];
        #pragma unroll
        for (int rr = 0; rr < K1R; ++rr) acc[rr] = bv;

        for (int k = 0; k < I_; ++k) {            // xe @ W
            f32x2 w = W2[k * 256 + tid];
            const f32x2* ap = (const f32x2*)&sA[k * K1P];
            #pragma unroll
            for (int rp = 0; rp < K1R / 2; ++rp) {
                f32x2 a = ap[rp];
                acc[2 * rp]     += a.x * w;
                acc[2 * rp + 1] += a.y * w;
            }
        }
        for (int k = 0; k < I_; ++k) {            // (1-m) @ V
            f32x2 w = V2[k * 256 + tid];
            const f32x2* ap = (const f32x2*)&sB[k * K1P];
            #pragma unroll
            for (int rp = 0; rp < K1R / 2; ++rp) {
                f32x2 a = ap[rp];
                acc[2 * rp]     += a.x * w;
                acc[2 * rp + 1] += a.y * w;
            }
        }
        f32x2* d2 = (f32x2*)dst;
        #pragma unroll
        for (int rr = 0; rr < K1R; ++rr) {
            int lr = lr0 + rr;
            int b = lr >> 4, tl = lr & 15;
            d2[(tl * B_ + b) * 256 + tid] = acc[rr];
        }
    } else {
        const f32x2* W2 = (const f32x2*)Wgh;
        f32x2 acc[K1R];
        f32x2 bv = ((const f32x2*)Bgh)[tid];
        #pragma unroll
        for (int rr = 0; rr < K1R; ++rr) acc[rr] = bv;
        for (int k = 0; k < I_; ++k) {
            f32x2 w = W2[k * 256 + tid];
            const f32x2* ap = (const f32x2*)&sA[k * K1P];
            #pragma unroll
            for (int rp = 0; rp < K1R / 2; ++rp) {
                f32x2 a = ap[rp];
                acc[2 * rp]     += a.x * w;
                acc[2 * rp + 1] += a.y * w;
            }
        }
        f32x2* d2 = (f32x2*)gm;
        #pragma unroll
        for (int rr = 0; rr < K1R; ++rr) {
            int lr = lr0 + rr;
            int b = lr >> 4, tl = lr & 15;
            f32x2 v;
            v.x = __expf(-fmaxf(acc[rr].x, 0.f));
            v.y = __expf(-fmaxf(acc[rr].y, 0.f));
            d2[(tl * B_ + b) * 256 + tid] = v;
        }
    }
}

// ---------------------------------------------------------------------------
// K2: sequential scan over one chunk. 128 blocks x 2 independent batch rows;
// h fp32 in registers (persisted in ws); U read as packed bf16 from L2.
// ---------------------------------------------------------------------------
__global__ __launch_bounds__(256) void k2_scan(
    const float* __restrict__ pz, const float* __restrict__ pr,
    const float* __restrict__ pc, const float* __restrict__ gm,
    const u32* __restrict__ Uzb, const u32* __restrict__ Urb,
    const u32* __restrict__ Ucb, float* __restrict__ hws)
{
    __shared__ f32x2 As[H_];    // As[k] = {A[row0][k], A[row1][k]}
    __shared__ f32x2 Ars[H_];
    const int tid = threadIdx.x;       // owns cols 2*tid, 2*tid+1
    const int b0 = blockIdx.x * 2;
    f32x2* hv = (f32x2*)hws;
    f32x2 h0 = hv[b0 * 256 + tid];
    f32x2 h1 = hv[(b0 + 1) * 256 + tid];

    for (int tl = 0; tl < CH; ++tl) {
        const int rb = (tl * B_ + b0) * 256;       // f32x2 index of row b0
        f32x2 g0 = ((const f32x2*)gm)[rb + tid];
        f32x2 g1 = ((const f32x2*)gm)[rb + 256 + tid];
        f32x2 a0 = g0 * h0;
        f32x2 a1 = g1 * h1;
        { f32x2 v; v.x = a0.x; v.y = a1.x; As[2 * tid] = v;
          v.x = a0.y; v.y = a1.y; As[2 * tid + 1] = v; }
        f32x2 az0 = ((const f32x2*)pz)[rb + tid];
        f32x2 az1 = ((const f32x2*)pz)[rb + 256 + tid];
        f32x2 ar0 = ((const f32x2*)pr)[rb + tid];
        f32x2 ar1 = ((const f32x2*)pr)[rb + 256 + tid];
        __syncthreads();
        #pragma unroll 8
        for (int k = 0; k < H_; ++k) {
            f32x2 a = As[k];
            f32x2 wz = bf2f(Uzb[k * 256 + tid]);
            f32x2 wr = bf2f(Urb[k * 256 + tid]);
            az0 += a.x * wz; az1 += a.y * wz;
            ar0 += a.x * wr; ar1 += a.y * wr;
        }
        f32x2 z0 = sigv(az0), z1 = sigv(az1);
        f32x2 r0 = sigv(ar0), r1 = sigv(ar1);
        { f32x2 v; v.x = a0.x * r0.x; v.y = a1.x * r1.x; Ars[2 * tid] = v;
          v.x = a0.y * r0.y; v.y = a1.y * r1.y; Ars[2 * tid + 1] = v; }
        f32x2 ac0 = ((const f32x2*)pc)[rb + tid];
        f32x2 ac1 = ((const f32x2*)pc)[rb + 256 + tid];
        __syncthreads();
        #pragma unroll 8
        for (int k = 0; k < H_; ++k) {
            f32x2 a = Ars[k];
            f32x2 wc = bf2f(Ucb[k * 256 + tid]);
            ac0 += a.x * wc; ac1 += a.y * wc;
        }
        f32x2 c0 = tanhv(ac0), c1 = tanhv(ac1);
        h0 = (1.f - z0) * a0 + z0 * c0;
        h1 = (1.f - z1) * a1 + z1 * c1;
        __syncthreads();
    }
    hv[b0 * 256 + tid] = h0;
    hv[(b0 + 1) * 256 + tid] = h1;
}

// ---------------------------------------------------------------------------
// K3: BatchNorm(eval) + decoder GEMV + log_softmax.
// out[0 : B*O]          = log_softmax(h_bn @ dec_W + dec_b)
// out[B*O : B*O + B*H]  = h_bn
// ---------------------------------------------------------------------------
__global__ __launch_bounds__(128) void k3_out(
    const float* __restrict__ hws,
    const float* __restrict__ dW, const float* __restrict__ db,
    const float* __restrict__ bng, const float* __restrict__ bnb,
    float* __restrict__ out)
{
    __shared__ float hb[H_];
    __shared__ float red[O_];
    const int tid = threadIdx.x;
    const int b = blockIdx.x;
    const float s = 0.9999950000374997f;   // 1/sqrt(1 + 1e-5)
    for (int k = tid; k < H_; k += O_) {
        float v = hws[b * H_ + k] * s * bng[k] + bnb[k];
        hb[k] = v;
        out[B_ * O_ + b * H_ + k] = v;
    }
    __syncthreads();
    float acc = db[tid];
    #pragma unroll 4
    for (int k = 0; k < H_; ++k) acc += hb[k] * dW[k * O_ + tid];
    red[tid] = acc;
    __syncthreads();
    for (int sh = 64; sh > 0; sh >>= 1) {
        if (tid < sh) red[tid] = fmaxf(red[tid], red[tid + sh]);
        __syncthreads();
    }
    float mx = red[0];
    __syncthreads();
    red[tid] = __expf(acc - mx);
    __syncthreads();
    for (int sh = 64; sh > 0; sh >>= 1) {
        if (tid < sh) red[tid] += red[tid + sh];
        __syncthreads();
    }
    float lse = __logf(red[0]) + mx;
    out[b * O_ + tid] = acc - lse;
}

extern "C" void kernel_launch(void* const* d_in, const int* in_sizes, int n_in,
                              void* d_out, int out_size, void* d_ws, size_t ws_size,
                              hipStream_t stream)
{
    (void)in_sizes; (void)n_in; (void)out_size; (void)ws_size;
    const float* x   = (const float*)d_in[0];
    const float* dl  = (const float*)d_in[1];
    const float* m   = (const float*)d_in[2];
    const float* xf  = (const float*)d_in[3];
    const float* Wr  = (const float*)d_in[4];
    const float* Ur  = (const float*)d_in[5];
    const float* Vr  = (const float*)d_in[6];
    const float* br  = (const float*)d_in[7];
    const float* Wz  = (const float*)d_in[8];
    const float* Uz  = (const float*)d_in[9];
    const float* Vz  = (const float*)d_in[10];
    const float* bz  = (const float*)d_in[11];
    const float* Wc  = (const float*)d_in[12];
    const float* Uc  = (const float*)d_in[13];
    const float* Vc  = (const float*)d_in[14];
    const float* bc  = (const float*)d_in[15];
    const float* Wgx = (const float*)d_in[16];
    const float* Bgx = (const float*)d_in[17];
    const float* Wgh = (const float*)d_in[18];
    const float* Bgh = (const float*)d_in[19];
    const float* dW  = (const float*)d_in[20];
    const float* db  = (const float*)d_in[21];
    const float* bng = (const float*)d_in[22];
    const float* bnb = (const float*)d_in[23];

    char* ws = (char*)d_ws;
    u32* Ub = (u32*)ws;                                   // 3*512*256 u32 = 1.5 MB
    const size_t UBYTES = (size_t)3 * H_ * 256 * 4;
    const size_t SZ = (size_t)CH * B_ * H_ * 4;           // 8 MB per fp32 pre-array
    float* pz  = (float*)(ws + UBYTES);
    float* pr  = (float*)(ws + UBYTES + SZ);
    float* pc  = (float*)(ws + UBYTES + 2 * SZ);
    float* gm  = (float*)(ws + UBYTES + 3 * SZ);
    float* hws = (float*)(ws + UBYTES + 4 * SZ);          // fp32 [B,H]

    hipMemsetAsync(hws, 0, (size_t)B_ * H_ * sizeof(float), stream);
    k_castU<<<dim3(3 * H_ * 256 / 256), dim3(256), 0, stream>>>(Uz, Ur, Uc, Ub);
    const u32* Uzb = Ub;
    const u32* Urb = Ub + H_ * 256;
    const u32* Ucb = Ub + 2 * H_ * 256;

    for (int c = 0; c < T_ / CH; ++c) {
        k1_pre<<<dim3((B_ * CH / K1R) * 4), dim3(256), 0, stream>>>(
            x, dl, m, xf, Wz, Vz, bz, Wr, Vr, br, Wc, Vc, bc,
            Wgx, Bgx, Wgh, Bgh, pz, pr, pc, gm, c * CH);
        k2_scan<<<dim3(B_ / 2), dim3(256), 0, stream>>>(
            pz, pr, pc, gm, Uzb, Urb, Ucb, hws);
    }
    k3_out<<<dim3(B_), dim3(O_), 0, stream>>>(hws, dW, db, bng, bnb, (float*)d_out);
}

// Round 3
// 6043.182 us; speedup vs baseline: 1.5636x; 1.5636x over previous
//
#include <hip/hip_runtime.h>
#include <stdint.h>

typedef float  f32x4 __attribute__((ext_vector_type(4)));
typedef short  s16x8 __attribute__((ext_vector_type(8)));
typedef unsigned int u32;

#define B_ 256
#define T_ 256
#define I_ 128
#define H_ 512
#define O_ 128
#define CH 16          // timesteps per chunk
#define A32LD 520      // padded leading dim for fp32 A in k2 LDS

__device__ __forceinline__ unsigned short f2b(float f) {
    u32 u = __float_as_uint(f);
    u += 0x7fffu + ((u >> 16) & 1u);       // RNE
    return (unsigned short)(u >> 16);
}
__device__ __forceinline__ float sigf(float x) { return 1.f / (1.f + __expf(-x)); }
__device__ __forceinline__ float tanhfast(float x) { return 1.f - 2.f / (__expf(2.f * x) + 1.f); }

// ===========================================================================
// k_pack: pack all weight matrices into MFMA B-fragment order, bf16.
// B-frag for 16x16x32: lane L holds B[k = kt*32 + (L>>4)*8 + j][n = nt*16 + (L&15)].
// PW[g][kt 0..7][nt 0..31]: kt<4 -> W_g rows kt*32.., kt>=4 -> V_g rows (kt-4)*32..
// PG[kt 0..3][nt]: W_gamma_h.      PU[g][kt 0..15][nt]: U_g.
// ===========================================================================
__global__ __launch_bounds__(256) void k_pack(
    const float* __restrict__ Wz, const float* __restrict__ Wr, const float* __restrict__ Wc,
    const float* __restrict__ Vz, const float* __restrict__ Vr, const float* __restrict__ Vc,
    const float* __restrict__ Wgh,
    const float* __restrict__ Uz, const float* __restrict__ Ur, const float* __restrict__ Uc,
    short* __restrict__ PW, short* __restrict__ PG, short* __restrict__ PU)
{
    int wv = blockIdx.x * 4 + (threadIdx.x >> 6);
    int L = threadIdx.x & 63;
    if (wv >= 2432) return;
    int koff = (L >> 4) << 3;
    const float* src; short* dst; int kbase, nt;
    if (wv < 768) {
        int g = wv >> 8, rem = wv & 255;
        int kt = rem >> 5; nt = rem & 31;
        src = (kt < 4) ? (g == 0 ? Wz : g == 1 ? Wr : Wc)
                       : (g == 0 ? Vz : g == 1 ? Vr : Vc);
        kbase = (kt & 3) * 32 + koff;
        dst = PW + ((size_t)(g * 256 + rem) * 64 + L) * 8;
    } else if (wv < 896) {
        int rem = wv - 768;
        nt = rem & 31;
        src = Wgh;
        kbase = (rem >> 5) * 32 + koff;
        dst = PG + ((size_t)rem * 64 + L) * 8;
    } else {
        int rem = wv - 896;
        int g = rem >> 9, r2 = rem & 511;
        nt = r2 & 31;
        src = (g == 0) ? Uz : (g == 1) ? Ur : Uc;
        kbase = (r2 >> 5) * 32 + koff;
        dst = PU + ((size_t)(g * 512 + r2) * 64 + L) * 8;
    }
    int n = nt * 16 + (L & 15);
    s16x8 v;
    #pragma unroll
    for (int j = 0; j < 8; ++j) v[j] = (short)f2b(src[(kbase + j) * H_ + n]);
    *(s16x8*)dst = v;
}

// ===========================================================================
// k1: MFMA input-side projections for one chunk. Block = 32 rows (2 mtiles),
// 256 threads (4 waves, each 128 cols). Row r = b*CH + tl.
// Outputs fp32: pz/pr/pc = xe@W + (1-m)@V + b  (layout [tl][b][H]),
// gm = exp(-relu(m@Wgh + bgh)).
// ===========================================================================
__global__ __launch_bounds__(256, 4) void k1_mfma(
    const float* __restrict__ x, const float* __restrict__ dl,
    const float* __restrict__ mk, const float* __restrict__ xf,
    const float* __restrict__ bz, const float* __restrict__ br, const float* __restrict__ bc,
    const float* __restrict__ Bgh,
    const float* __restrict__ Wgx, const float* __restrict__ Bgx,
    const short* __restrict__ PW, const short* __restrict__ PG,
    float* __restrict__ pz, float* __restrict__ pr, float* __restrict__ pc,
    float* __restrict__ gm, int t0)
{
    __shared__ short Abuf[2 * 12 * 64 * 8];   // [mt][kt 0..11][lane][8], 24 KB
    const int tid = threadIdx.x;
    const int L = tid & 63;
    const int w = tid >> 6;
    const int lr0 = blockIdx.x * 32;

    // stage A-fragments: kt 0..3 = xe, 4..7 = 1-m, 8..11 = m
    for (int c = tid; c < 1536; c += 256) {
        int Ls = c & 63, rem = c >> 6;
        int kt = rem % 12, mt = rem / 12;
        int mrow = Ls & 15, q = Ls >> 4;
        int r = lr0 + mt * 16 + mrow;
        int b = r >> 4, tl = r & 15;
        int gbase = (b * T_ + t0 + tl) * I_;
        s16x8 v;
        if (kt < 4) {
            int kb = kt * 32 + q * 8;
            #pragma unroll
            for (int j = 0; j < 8; ++j) {
                int k = kb + j, gi = gbase + k;
                float mv = mk[gi];
                float dx = dl[gi] * Wgx[k] + Bgx[k];
                float xr = dx * xf[gi] + (1.f - dx) * 0.001f;
                float xe = (mv > 0.5f) ? xr : x[gi];
                v[j] = (short)f2b(xe);
            }
        } else if (kt < 8) {
            int kb = (kt - 4) * 32 + q * 8;
            #pragma unroll
            for (int j = 0; j < 8; ++j) v[j] = (short)f2b(1.f - mk[gbase + kb + j]);
        } else {
            int kb = (kt - 8) * 32 + q * 8;
            #pragma unroll
            for (int j = 0; j < 8; ++j) v[j] = (short)f2b(mk[gbase + kb + j]);
        }
        *(s16x8*)&Abuf[(size_t)c * 8] = v;
    }
    __syncthreads();

    const s16x8* PWf = (const s16x8*)PW;
    const s16x8* PGf = (const s16x8*)PG;

    // gates z, r, c
    for (int g = 0; g < 3; ++g) {
        f32x4 acc[2][8];
        #pragma unroll
        for (int mt = 0; mt < 2; ++mt)
            #pragma unroll
            for (int nt = 0; nt < 8; ++nt) acc[mt][nt] = (f32x4)0.f;
        for (int kt = 0; kt < 8; ++kt) {
            s16x8 a0 = *(const s16x8*)&Abuf[((0 * 12 + kt) * 64 + L) * 8];
            s16x8 a1 = *(const s16x8*)&Abuf[((1 * 12 + kt) * 64 + L) * 8];
            const s16x8* pw = PWf + ((size_t)(g * 256 + kt * 32 + w * 8) * 64 + L);
            #pragma unroll
            for (int nt = 0; nt < 8; ++nt) {
                s16x8 bfr = pw[(size_t)nt * 64];
                acc[0][nt] = __builtin_amdgcn_mfma_f32_16x16x32_bf16(a0, bfr, acc[0][nt], 0, 0, 0);
                acc[1][nt] = __builtin_amdgcn_mfma_f32_16x16x32_bf16(a1, bfr, acc[1][nt], 0, 0, 0);
            }
        }
        const float* bias = (g == 0) ? bz : (g == 1) ? br : bc;
        float* dst = (g == 0) ? pz : (g == 1) ? pr : pc;
        #pragma unroll
        for (int nt = 0; nt < 8; ++nt) {
            int n = w * 128 + nt * 16 + (L & 15);
            float bv = bias[n];
            #pragma unroll
            for (int mt = 0; mt < 2; ++mt)
                #pragma unroll
                for (int reg = 0; reg < 4; ++reg) {
                    int r = lr0 + mt * 16 + (L >> 4) * 4 + reg;
                    int b = r >> 4, tl = r & 15;
                    dst[(size_t)(tl * B_ + b) * H_ + n] = acc[mt][nt][reg] + bv;
                }
        }
    }
    // gamma_h
    {
        f32x4 acc[2][8];
        #pragma unroll
        for (int mt = 0; mt < 2; ++mt)
            #pragma unroll
            for (int nt = 0; nt < 8; ++nt) acc[mt][nt] = (f32x4)0.f;
        for (int kk = 0; kk < 4; ++kk) {
            s16x8 a0 = *(const s16x8*)&Abuf[((0 * 12 + 8 + kk) * 64 + L) * 8];
            s16x8 a1 = *(const s16x8*)&Abuf[((1 * 12 + 8 + kk) * 64 + L) * 8];
            const s16x8* pg = PGf + ((size_t)(kk * 32 + w * 8) * 64 + L);
            #pragma unroll
            for (int nt = 0; nt < 8; ++nt) {
                s16x8 bfr = pg[(size_t)nt * 64];
                acc[0][nt] = __builtin_amdgcn_mfma_f32_16x16x32_bf16(a0, bfr, acc[0][nt], 0, 0, 0);
                acc[1][nt] = __builtin_amdgcn_mfma_f32_16x16x32_bf16(a1, bfr, acc[1][nt], 0, 0, 0);
            }
        }
        #pragma unroll
        for (int nt = 0; nt < 8; ++nt) {
            int n = w * 128 + nt * 16 + (L & 15);
            float bv = Bgh[n];
            #pragma unroll
            for (int mt = 0; mt < 2; ++mt)
                #pragma unroll
                for (int reg = 0; reg < 4; ++reg) {
                    int r = lr0 + mt * 16 + (L >> 4) * 4 + reg;
                    int b = r >> 4, tl = r & 15;
                    gm[(size_t)(tl * B_ + b) * H_ + n] = __expf(-fmaxf(acc[mt][nt][reg] + bv, 0.f));
                }
        }
    }
}

// ===========================================================================
// k2: MFMA sequential scan. 16 blocks x 1024 threads; block owns 16 batch
// rows; wave w owns cols [w*32, w*32+32). Carry state A = gamma*h held fp32
// in LDS; bf16 copies only feed MFMA. 2 barriers/step.
// ===========================================================================
__global__ __launch_bounds__(1024) void k2_mfma(
    const float* __restrict__ pz, const float* __restrict__ pr,
    const float* __restrict__ pc, const float* __restrict__ gm,
    const short* __restrict__ PU, float* __restrict__ hws, int last_chunk)
{
    __shared__ float A32[16 * A32LD];         // fp32 A = gamma*h, padded rows
    __shared__ short Abf[16 * 64 * 8];        // A bf16 fragments   [kt][lane][8]
    __shared__ short Apbf[16 * 64 * 8];       // (A*r) bf16 fragments
    const int tid = threadIdx.x;
    const int L = tid & 63;
    const int w = tid >> 6;
    const int b0 = blockIdx.x * 16;
    const s16x8* PUf = (const s16x8*)PU;

    // phase 0: A = gamma[t=0] * h   (h from global, fp32)
    {
        int base = tid * 8;
        int m = base >> 9, n0 = base & 511;
        f32x4 h0 = *(const f32x4*)&hws[(size_t)(b0 + m) * H_ + n0];
        f32x4 h1 = *(const f32x4*)&hws[(size_t)(b0 + m) * H_ + n0 + 4];
        f32x4 g0 = *(const f32x4*)&gm[(size_t)(b0 + m) * H_ + n0];
        f32x4 g1 = *(const f32x4*)&gm[(size_t)(b0 + m) * H_ + n0 + 4];
        f32x4 a0 = g0 * h0, a1 = g1 * h1;
        *(f32x4*)&A32[m * A32LD + n0] = a0;
        *(f32x4*)&A32[m * A32LD + n0 + 4] = a1;
        int kt = n0 >> 5, q = (n0 >> 3) & 3;
        s16x8 v;
        #pragma unroll
        for (int j = 0; j < 4; ++j) { v[j] = (short)f2b(a0[j]); v[4 + j] = (short)f2b(a1[j]); }
        *(s16x8*)&Abf[((kt * 64) + (m | (q << 4))) * 8] = v;
    }
    __syncthreads();

    for (int tl = 0; tl < CH; ++tl) {
        // ---- phase 1: z,r GEMMs ----
        f32x4 az[2], ar[2];
        az[0] = (f32x4)0.f; az[1] = (f32x4)0.f;
        ar[0] = (f32x4)0.f; ar[1] = (f32x4)0.f;
        #pragma unroll 4
        for (int kt = 0; kt < 16; ++kt) {
            s16x8 a = *(const s16x8*)&Abf[(kt * 64 + L) * 8];
            const s16x8* pz_ = PUf + ((size_t)(0 * 512 + kt * 32 + w * 2) * 64 + L);
            const s16x8* pr_ = PUf + ((size_t)(1 * 512 + kt * 32 + w * 2) * 64 + L);
            s16x8 bz0 = pz_[0], bz1 = pz_[64];
            s16x8 br0 = pr_[0], br1 = pr_[64];
            az[0] = __builtin_amdgcn_mfma_f32_16x16x32_bf16(a, bz0, az[0], 0, 0, 0);
            az[1] = __builtin_amdgcn_mfma_f32_16x16x32_bf16(a, bz1, az[1], 0, 0, 0);
            ar[0] = __builtin_amdgcn_mfma_f32_16x16x32_bf16(a, br0, ar[0], 0, 0, 0);
            ar[1] = __builtin_amdgcn_mfma_f32_16x16x32_bf16(a, br1, ar[1], 0, 0, 0);
        }
        float zv[2][4];
        #pragma unroll
        for (int nt = 0; nt < 2; ++nt) {
            int n = w * 32 + nt * 16 + (L & 15);
            int kt2 = n >> 5, q2 = (n >> 3) & 3, j2 = n & 7;
            #pragma unroll
            for (int reg = 0; reg < 4; ++reg) {
                int row = (L >> 4) * 4 + reg;
                size_t idx = (size_t)(tl * B_ + b0 + row) * H_ + n;
                float z = sigf(az[nt][reg] + pz[idx]);
                float r = sigf(ar[nt][reg] + pr[idx]);
                zv[nt][reg] = z;
                float ap = A32[row * A32LD + n] * r;
                Apbf[((kt2 * 64) + (row | (q2 << 4))) * 8 + j2] = (short)f2b(ap);
            }
        }
        __syncthreads();

        // ---- phase 2: c GEMM + state update ----
        f32x4 ac[2];
        ac[0] = (f32x4)0.f; ac[1] = (f32x4)0.f;
        #pragma unroll 4
        for (int kt = 0; kt < 16; ++kt) {
            s16x8 a = *(const s16x8*)&Apbf[(kt * 64 + L) * 8];
            const s16x8* pc_ = PUf + ((size_t)(2 * 512 + kt * 32 + w * 2) * 64 + L);
            s16x8 bc0 = pc_[0], bc1 = pc_[64];
            ac[0] = __builtin_amdgcn_mfma_f32_16x16x32_bf16(a, bc0, ac[0], 0, 0, 0);
            ac[1] = __builtin_amdgcn_mfma_f32_16x16x32_bf16(a, bc1, ac[1], 0, 0, 0);
        }
        #pragma unroll
        for (int nt = 0; nt < 2; ++nt) {
            int n = w * 32 + nt * 16 + (L & 15);
            int kt2 = n >> 5, q2 = (n >> 3) & 3, j2 = n & 7;
            #pragma unroll
            for (int reg = 0; reg < 4; ++reg) {
                int row = (L >> 4) * 4 + reg;
                size_t idx = (size_t)(tl * B_ + b0 + row) * H_ + n;
                float c = tanhfast(ac[nt][reg] + pc[idx]);
                float a32 = A32[row * A32LD + n];
                float z = zv[nt][reg];
                float hn = (1.f - z) * a32 + z * c;
                if (tl < CH - 1) {
                    float gn = gm[(size_t)((tl + 1) * B_ + b0 + row) * H_ + n];
                    float An = gn * hn;
                    A32[row * A32LD + n] = An;
                    Abf[((kt2 * 64) + (row | (q2 << 4))) * 8 + j2] = (short)f2b(An);
                } else {
                    hws[(size_t)(b0 + row) * H_ + n] = hn;
                }
            }
        }
        __syncthreads();
    }
    (void)last_chunk;
}

// ===========================================================================
// k3: BatchNorm(eval) + decoder GEMV + log_softmax.
// ===========================================================================
__global__ __launch_bounds__(128) void k3_out(
    const float* __restrict__ hws,
    const float* __restrict__ dW, const float* __restrict__ db,
    const float* __restrict__ bng, const float* __restrict__ bnb,
    float* __restrict__ out)
{
    __shared__ float hb[H_];
    __shared__ float red[O_];
    const int tid = threadIdx.x;
    const int b = blockIdx.x;
    const float s = 0.9999950000374997f;   // 1/sqrt(1 + 1e-5)
    for (int k = tid; k < H_; k += O_) {
        float v = hws[(size_t)b * H_ + k] * s * bng[k] + bnb[k];
        hb[k] = v;
        out[B_ * O_ + (size_t)b * H_ + k] = v;
    }
    __syncthreads();
    float acc = db[tid];
    #pragma unroll 4
    for (int k = 0; k < H_; ++k) acc += hb[k] * dW[(size_t)k * O_ + tid];
    red[tid] = acc;
    __syncthreads();
    for (int sh = 64; sh > 0; sh >>= 1) {
        if (tid < sh) red[tid] = fmaxf(red[tid], red[tid + sh]);
        __syncthreads();
    }
    float mx = red[0];
    __syncthreads();
    red[tid] = __expf(acc - mx);
    __syncthreads();
    for (int sh = 64; sh > 0; sh >>= 1) {
        if (tid < sh) red[tid] += red[tid + sh];
        __syncthreads();
    }
    float lse = __logf(red[0]) + mx;
    out[(size_t)b * O_ + tid] = acc - lse;
}

extern "C" void kernel_launch(void* const* d_in, const int* in_sizes, int n_in,
                              void* d_out, int out_size, void* d_ws, size_t ws_size,
                              hipStream_t stream)
{
    (void)in_sizes; (void)n_in; (void)out_size; (void)ws_size;
    const float* x   = (const float*)d_in[0];
    const float* dl  = (const float*)d_in[1];
    const float* m   = (const float*)d_in[2];
    const float* xf  = (const float*)d_in[3];
    const float* Wr  = (const float*)d_in[4];
    const float* Ur  = (const float*)d_in[5];
    const float* Vr  = (const float*)d_in[6];
    const float* br  = (const float*)d_in[7];
    const float* Wz  = (const float*)d_in[8];
    const float* Uz  = (const float*)d_in[9];
    const float* Vz  = (const float*)d_in[10];
    const float* bz  = (const float*)d_in[11];
    const float* Wc  = (const float*)d_in[12];
    const float* Uc  = (const float*)d_in[13];
    const float* Vc  = (const float*)d_in[14];
    const float* bc  = (const float*)d_in[15];
    const float* Wgx = (const float*)d_in[16];
    const float* Bgx = (const float*)d_in[17];
    const float* Wgh = (const float*)d_in[18];
    const float* Bgh = (const float*)d_in[19];
    const float* dW  = (const float*)d_in[20];
    const float* db  = (const float*)d_in[21];
    const float* bng = (const float*)d_in[22];
    const float* bnb = (const float*)d_in[23];

    char* ws = (char*)d_ws;
    short* PW = (short*)ws;                            // 3*256*64*8 shorts = 768 KB
    short* PG = PW + 3 * 256 * 64 * 8;                 // 128*64*8 shorts = 128 KB
    short* PU = PG + 128 * 64 * 8;                     // 3*512*64*8 shorts = 1.5 MB
    char* ws2 = (char*)(PU + 3 * 512 * 64 * 8);
    const size_t SZ = (size_t)CH * B_ * H_ * 4;        // 8 MB per fp32 chunk array
    float* pz  = (float*)(ws2);
    float* pr  = (float*)(ws2 + SZ);
    float* pc  = (float*)(ws2 + 2 * SZ);
    float* gm  = (float*)(ws2 + 3 * SZ);
    float* hws = (float*)(ws2 + 4 * SZ);               // fp32 [B,H]

    hipMemsetAsync(hws, 0, (size_t)B_ * H_ * sizeof(float), stream);
    k_pack<<<dim3(608), dim3(256), 0, stream>>>(Wz, Wr, Wc, Vz, Vr, Vc, Wgh,
                                                Uz, Ur, Uc, PW, PG, PU);
    for (int c = 0; c < T_ / CH; ++c) {
        k1_mfma<<<dim3(B_ * CH / 32), dim3(256), 0, stream>>>(
            x, dl, m, xf, bz, br, bc, Bgh, Wgx, Bgx, PW, PG,
            pz, pr, pc, gm, c * CH);
        k2_mfma<<<dim3(B_ / 16), dim3(1024), 0, stream>>>(
            pz, pr, pc, gm, PU, hws, c == T_ / CH - 1);
    }
    k3_out<<<dim3(B_), dim3(O_), 0, stream>>>(hws, dW, db, bng, bnb, (float*)d_out);
}

// Round 4
// 4392.170 us; speedup vs baseline: 2.1513x; 1.3759x over previous
//
#include <hip/hip_runtime.h>
#include <stdint.h>

typedef float  f32x4 __attribute__((ext_vector_type(4)));
typedef short  s16x8 __attribute__((ext_vector_type(8)));
typedef unsigned int u32;

#define B_ 256
#define T_ 256
#define I_ 128
#define H_ 512
#define O_ 128
#define CH 16          // timesteps per chunk

__device__ __forceinline__ unsigned short f2b(float f) {
    u32 u = __float_as_uint(f);
    u += 0x7fffu + ((u >> 16) & 1u);       // RNE
    return (unsigned short)(u >> 16);
}
__device__ __forceinline__ float sigf(float x) { return 1.f / (1.f + __expf(-x)); }
__device__ __forceinline__ float tanhfast(float x) { return 1.f - 2.f / (__expf(2.f * x) + 1.f); }

// ===========================================================================
// k_pack: pack weights into MFMA B-fragment order, bf16.
// B-frag 16x16x32: lane L holds B[k = kt*32 + (L>>4)*8 + j][n = nt*16 + (L&15)].
// PW[g][kt 0..7][nt 0..31]: kt<4 -> W_g, kt>=4 -> V_g.  PG[kt 0..3][nt]: Wgh.
// PU[g][kt 0..15][nt 0..31]: U_g.
// ===========================================================================
__global__ __launch_bounds__(256) void k_pack(
    const float* __restrict__ Wz, const float* __restrict__ Wr, const float* __restrict__ Wc,
    const float* __restrict__ Vz, const float* __restrict__ Vr, const float* __restrict__ Vc,
    const float* __restrict__ Wgh,
    const float* __restrict__ Uz, const float* __restrict__ Ur, const float* __restrict__ Uc,
    short* __restrict__ PW, short* __restrict__ PG, short* __restrict__ PU)
{
    int wv = blockIdx.x * 4 + (threadIdx.x >> 6);
    int L = threadIdx.x & 63;
    if (wv >= 2432) return;
    int koff = (L >> 4) << 3;
    const float* src; short* dst; int kbase, nt;
    if (wv < 768) {
        int g = wv >> 8, rem = wv & 255;
        int kt = rem >> 5; nt = rem & 31;
        src = (kt < 4) ? (g == 0 ? Wz : g == 1 ? Wr : Wc)
                       : (g == 0 ? Vz : g == 1 ? Vr : Vc);
        kbase = (kt & 3) * 32 + koff;
        dst = PW + ((size_t)(g * 256 + rem) * 64 + L) * 8;
    } else if (wv < 896) {
        int rem = wv - 768;
        nt = rem & 31;
        src = Wgh;
        kbase = (rem >> 5) * 32 + koff;
        dst = PG + ((size_t)rem * 64 + L) * 8;
    } else {
        int rem = wv - 896;
        int g = rem >> 9, r2 = rem & 511;
        nt = r2 & 31;
        src = (g == 0) ? Uz : (g == 1) ? Ur : Uc;
        kbase = (r2 >> 5) * 32 + koff;
        dst = PU + ((size_t)(g * 512 + r2) * 64 + L) * 8;
    }
    int n = nt * 16 + (L & 15);
    s16x8 v;
    #pragma unroll
    for (int j = 0; j < 8; ++j) v[j] = (short)f2b(src[(kbase + j) * H_ + n]);
    *(s16x8*)dst = v;
}

// ===========================================================================
// k1: input-side projections. 256 blocks (one per batch row b = blockIdx.x),
// 512 threads = 8 waves; wave w owns cols [w*64, w*64+64). One 16-row m-tile
// covering tl = 0..15 of the chunk.
// ===========================================================================
__global__ __launch_bounds__(512) void k1_mfma(
    const float* __restrict__ x, const float* __restrict__ dl,
    const float* __restrict__ mk, const float* __restrict__ xf,
    const float* __restrict__ bz, const float* __restrict__ br, const float* __restrict__ bc,
    const float* __restrict__ Bgh,
    const float* __restrict__ Wgx, const float* __restrict__ Bgx,
    const short* __restrict__ PW, const short* __restrict__ PG,
    float* __restrict__ pz, float* __restrict__ pr, float* __restrict__ pc,
    float* __restrict__ gm, int t0)
{
    __shared__ short Abuf[12 * 64 * 8];   // [kt 0..11][lane][8]; 0-3 xe, 4-7 1-m, 8-11 m
    const int tid = threadIdx.x;
    const int L = tid & 63;
    const int w = tid >> 6;
    const int b = blockIdx.x;

    for (int c = tid; c < 12 * 64; c += 512) {
        int Ls = c & 63, kt = c >> 6;
        int tl = Ls & 15, q = Ls >> 4;
        int gbase = (b * T_ + t0 + tl) * I_;
        s16x8 v;
        if (kt < 4) {
            int kb = kt * 32 + q * 8;
            #pragma unroll
            for (int j = 0; j < 8; ++j) {
                int k = kb + j, gi = gbase + k;
                float mv = mk[gi];
                float dx = dl[gi] * Wgx[k] + Bgx[k];
                float xr = dx * xf[gi] + (1.f - dx) * 0.001f;
                v[j] = (short)f2b((mv > 0.5f) ? xr : x[gi]);
            }
        } else if (kt < 8) {
            int kb = (kt - 4) * 32 + q * 8;
            #pragma unroll
            for (int j = 0; j < 8; ++j) v[j] = (short)f2b(1.f - mk[gbase + kb + j]);
        } else {
            int kb = (kt - 8) * 32 + q * 8;
            #pragma unroll
            for (int j = 0; j < 8; ++j) v[j] = (short)f2b(mk[gbase + kb + j]);
        }
        *(s16x8*)&Abuf[(size_t)c * 8] = v;
    }
    __syncthreads();

    const s16x8* PWf = (const s16x8*)PW;
    const s16x8* PGf = (const s16x8*)PG;

    for (int g = 0; g < 3; ++g) {
        f32x4 acc[4];
        #pragma unroll
        for (int nt = 0; nt < 4; ++nt) acc[nt] = (f32x4)0.f;
        for (int kt = 0; kt < 8; ++kt) {
            s16x8 a = *(const s16x8*)&Abuf[(kt * 64 + L) * 8];
            const s16x8* pw = PWf + ((size_t)(g * 256 + kt * 32 + w * 4) * 64 + L);
            #pragma unroll
            for (int nt = 0; nt < 4; ++nt)
                acc[nt] = __builtin_amdgcn_mfma_f32_16x16x32_bf16(a, pw[(size_t)nt * 64], acc[nt], 0, 0, 0);
        }
        const float* bias = (g == 0) ? bz : (g == 1) ? br : bc;
        float* dst = (g == 0) ? pz : (g == 1) ? pr : pc;
        #pragma unroll
        for (int nt = 0; nt < 4; ++nt) {
            int n = w * 64 + nt * 16 + (L & 15);
            float bv = bias[n];
            #pragma unroll
            for (int reg = 0; reg < 4; ++reg) {
                int tl = (L >> 4) * 4 + reg;
                dst[(size_t)(tl * B_ + b) * H_ + n] = acc[nt][reg] + bv;
            }
        }
    }
    {
        f32x4 acc[4];
        #pragma unroll
        for (int nt = 0; nt < 4; ++nt) acc[nt] = (f32x4)0.f;
        for (int kk = 0; kk < 4; ++kk) {
            s16x8 a = *(const s16x8*)&Abuf[((8 + kk) * 64 + L) * 8];
            const s16x8* pg = PGf + ((size_t)(kk * 32 + w * 4) * 64 + L);
            #pragma unroll
            for (int nt = 0; nt < 4; ++nt)
                acc[nt] = __builtin_amdgcn_mfma_f32_16x16x32_bf16(a, pg[(size_t)nt * 64], acc[nt], 0, 0, 0);
        }
        #pragma unroll
        for (int nt = 0; nt < 4; ++nt) {
            int n = w * 64 + nt * 16 + (L & 15);
            float bv = Bgh[n];
            #pragma unroll
            for (int reg = 0; reg < 4; ++reg) {
                int tl = (L >> 4) * 4 + reg;
                gm[(size_t)(tl * B_ + b) * H_ + n] = __expf(-fmaxf(acc[nt][reg] + bv, 0.f));
            }
        }
    }
}

// ===========================================================================
// k2: MFMA sequential scan. 16 blocks x 1024 threads; block owns 16 batch
// rows; wave w owns cols [w*32, w*32+32). Carry A = gamma*h in REGISTERS
// (thread owns the same 8 (row,n) elements in both phases); bf16 fragment
// copies in LDS feed MFMA. All p*/gm loads hoisted before the MFMA loop.
// ===========================================================================
__global__ __launch_bounds__(1024) void k2_mfma(
    const float* __restrict__ pz, const float* __restrict__ pr,
    const float* __restrict__ pc, const float* __restrict__ gm,
    const short* __restrict__ PU, float* __restrict__ hws)
{
    __shared__ short Abf[16 * 64 * 8];        // A fragments   [kt][lane][8]
    __shared__ short Apbf[16 * 64 * 8];       // (A*r) fragments
    const int tid = threadIdx.x;
    const int L = tid & 63;
    const int w = tid >> 6;
    const int b0 = blockIdx.x * 16;
    const s16x8* PUf = (const s16x8*)PU;

    // thread's 8 elements: row = (L>>4)*4+reg, n = w*32 + nt*16 + (L&15)
    float Areg[2][4];
    #pragma unroll
    for (int nt = 0; nt < 2; ++nt) {
        int n = w * 32 + nt * 16 + (L & 15);
        int kt2 = n >> 5, q2 = (n >> 3) & 3, j2 = n & 7;
        #pragma unroll
        for (int reg = 0; reg < 4; ++reg) {
            int row = (L >> 4) * 4 + reg;
            float h = hws[(size_t)(b0 + row) * H_ + n];
            float g = gm[(size_t)(b0 + row) * H_ + n];     // tl = 0
            float A = g * h;
            Areg[nt][reg] = A;
            Abf[((kt2 * 64) + (row | (q2 << 4))) * 8 + j2] = (short)f2b(A);
        }
    }
    __syncthreads();

    for (int tl = 0; tl < CH; ++tl) {
        // ---- hoisted loads for this step (land during the MFMA loop) ----
        float lpz[2][4], lpr[2][4], lpc[2][4], lgm[2][4];
        {
            int tln = (tl + 1 < CH) ? tl + 1 : tl;    // clamped; unused at tl==CH-1
            #pragma unroll
            for (int nt = 0; nt < 2; ++nt) {
                int n = w * 32 + nt * 16 + (L & 15);
                #pragma unroll
                for (int reg = 0; reg < 4; ++reg) {
                    int row = (L >> 4) * 4 + reg;
                    size_t idx = (size_t)(tl * B_ + b0 + row) * H_ + n;
                    lpz[nt][reg] = pz[idx];
                    lpr[nt][reg] = pr[idx];
                    lpc[nt][reg] = pc[idx];
                    lgm[nt][reg] = gm[(size_t)(tln * B_ + b0 + row) * H_ + n];
                }
            }
        }

        // ---- phase 1: z,r GEMMs ----
        f32x4 az[2], ar[2];
        az[0] = (f32x4)0.f; az[1] = (f32x4)0.f;
        ar[0] = (f32x4)0.f; ar[1] = (f32x4)0.f;
        #pragma unroll 4
        for (int kt = 0; kt < 16; ++kt) {
            s16x8 a = *(const s16x8*)&Abf[(kt * 64 + L) * 8];
            const s16x8* pz_ = PUf + ((size_t)(0 * 512 + kt * 32 + w * 2) * 64 + L);
            const s16x8* pr_ = PUf + ((size_t)(1 * 512 + kt * 32 + w * 2) * 64 + L);
            s16x8 bz0 = pz_[0], bz1 = pz_[64];
            s16x8 br0 = pr_[0], br1 = pr_[64];
            az[0] = __builtin_amdgcn_mfma_f32_16x16x32_bf16(a, bz0, az[0], 0, 0, 0);
            az[1] = __builtin_amdgcn_mfma_f32_16x16x32_bf16(a, bz1, az[1], 0, 0, 0);
            ar[0] = __builtin_amdgcn_mfma_f32_16x16x32_bf16(a, br0, ar[0], 0, 0, 0);
            ar[1] = __builtin_amdgcn_mfma_f32_16x16x32_bf16(a, br1, ar[1], 0, 0, 0);
        }
        float zv[2][4];
        #pragma unroll
        for (int nt = 0; nt < 2; ++nt) {
            int n = w * 32 + nt * 16 + (L & 15);
            int kt2 = n >> 5, q2 = (n >> 3) & 3, j2 = n & 7;
            #pragma unroll
            for (int reg = 0; reg < 4; ++reg) {
                int row = (L >> 4) * 4 + reg;
                float z = sigf(az[nt][reg] + lpz[nt][reg]);
                float r = sigf(ar[nt][reg] + lpr[nt][reg]);
                zv[nt][reg] = z;
                float ap = Areg[nt][reg] * r;
                Apbf[((kt2 * 64) + (row | (q2 << 4))) * 8 + j2] = (short)f2b(ap);
            }
        }
        __syncthreads();

        // ---- phase 2: c GEMM + state update ----
        f32x4 ac[2];
        ac[0] = (f32x4)0.f; ac[1] = (f32x4)0.f;
        #pragma unroll 4
        for (int kt = 0; kt < 16; ++kt) {
            s16x8 a = *(const s16x8*)&Apbf[(kt * 64 + L) * 8];
            const s16x8* pc_ = PUf + ((size_t)(2 * 512 + kt * 32 + w * 2) * 64 + L);
            s16x8 bc0 = pc_[0], bc1 = pc_[64];
            ac[0] = __builtin_amdgcn_mfma_f32_16x16x32_bf16(a, bc0, ac[0], 0, 0, 0);
            ac[1] = __builtin_amdgcn_mfma_f32_16x16x32_bf16(a, bc1, ac[1], 0, 0, 0);
        }
        #pragma unroll
        for (int nt = 0; nt < 2; ++nt) {
            int n = w * 32 + nt * 16 + (L & 15);
            int kt2 = n >> 5, q2 = (n >> 3) & 3, j2 = n & 7;
            #pragma unroll
            for (int reg = 0; reg < 4; ++reg) {
                int row = (L >> 4) * 4 + reg;
                float c = tanhfast(ac[nt][reg] + lpc[nt][reg]);
                float z = zv[nt][reg];
                float hn = (1.f - z) * Areg[nt][reg] + z * c;
                if (tl < CH - 1) {
                    float An = lgm[nt][reg] * hn;
                    Areg[nt][reg] = An;
                    Abf[((kt2 * 64) + (row | (q2 << 4))) * 8 + j2] = (short)f2b(An);
                } else {
                    hws[(size_t)(b0 + row) * H_ + n] = hn;
                }
            }
        }
        __syncthreads();
    }
}

// ===========================================================================
// k3: BatchNorm(eval) + decoder GEMV + log_softmax.
// ===========================================================================
__global__ __launch_bounds__(128) void k3_out(
    const float* __restrict__ hws,
    const float* __restrict__ dW, const float* __restrict__ db,
    const float* __restrict__ bng, const float* __restrict__ bnb,
    float* __restrict__ out)
{
    __shared__ float hb[H_];
    __shared__ float red[O_];
    const int tid = threadIdx.x;
    const int b = blockIdx.x;
    const float s = 0.9999950000374997f;   // 1/sqrt(1 + 1e-5)
    for (int k = tid; k < H_; k += O_) {
        float v = hws[(size_t)b * H_ + k] * s * bng[k] + bnb[k];
        hb[k] = v;
        out[B_ * O_ + (size_t)b * H_ + k] = v;
    }
    __syncthreads();
    float acc = db[tid];
    #pragma unroll 4
    for (int k = 0; k < H_; ++k) acc += hb[k] * dW[(size_t)k * O_ + tid];
    red[tid] = acc;
    __syncthreads();
    for (int sh = 64; sh > 0; sh >>= 1) {
        if (tid < sh) red[tid] = fmaxf(red[tid], red[tid + sh]);
        __syncthreads();
    }
    float mx = red[0];
    __syncthreads();
    red[tid] = __expf(acc - mx);
    __syncthreads();
    for (int sh = 64; sh > 0; sh >>= 1) {
        if (tid < sh) red[tid] += red[tid + sh];
        __syncthreads();
    }
    float lse = __logf(red[0]) + mx;
    out[(size_t)b * O_ + tid] = acc - lse;
}

extern "C" void kernel_launch(void* const* d_in, const int* in_sizes, int n_in,
                              void* d_out, int out_size, void* d_ws, size_t ws_size,
                              hipStream_t stream)
{
    (void)in_sizes; (void)n_in; (void)out_size; (void)ws_size;
    const float* x   = (const float*)d_in[0];
    const float* dl  = (const float*)d_in[1];
    const float* m   = (const float*)d_in[2];
    const float* xf  = (const float*)d_in[3];
    const float* Wr  = (const float*)d_in[4];
    const float* Ur  = (const float*)d_in[5];
    const float* Vr  = (const float*)d_in[6];
    const float* br  = (const float*)d_in[7];
    const float* Wz  = (const float*)d_in[8];
    const float* Uz  = (const float*)d_in[9];
    const float* Vz  = (const float*)d_in[10];
    const float* bz  = (const float*)d_in[11];
    const float* Wc  = (const float*)d_in[12];
    const float* Uc  = (const float*)d_in[13];
    const float* Vc  = (const float*)d_in[14];
    const float* bc  = (const float*)d_in[15];
    const float* Wgx = (const float*)d_in[16];
    const float* Bgx = (const float*)d_in[17];
    const float* Wgh = (const float*)d_in[18];
    const float* Bgh = (const float*)d_in[19];
    const float* dW  = (const float*)d_in[20];
    const float* db  = (const float*)d_in[21];
    const float* bng = (const float*)d_in[22];
    const float* bnb = (const float*)d_in[23];

    char* ws = (char*)d_ws;
    short* PW = (short*)ws;                            // 768 KB
    short* PG = PW + 3 * 256 * 64 * 8;                 // 128 KB
    short* PU = PG + 128 * 64 * 8;                     // 1.5 MB
    char* ws2 = (char*)(PU + 3 * 512 * 64 * 8);
    const size_t SZ = (size_t)CH * B_ * H_ * 4;        // 8 MB per fp32 chunk array
    float* pz  = (float*)(ws2);
    float* pr  = (float*)(ws2 + SZ);
    float* pc  = (float*)(ws2 + 2 * SZ);
    float* gm  = (float*)(ws2 + 3 * SZ);
    float* hws = (float*)(ws2 + 4 * SZ);               // fp32 [B,H]

    hipMemsetAsync(hws, 0, (size_t)B_ * H_ * sizeof(float), stream);
    k_pack<<<dim3(608), dim3(256), 0, stream>>>(Wz, Wr, Wc, Vz, Vr, Vc, Wgh,
                                                Uz, Ur, Uc, PW, PG, PU);
    for (int c = 0; c < T_ / CH; ++c) {
        k1_mfma<<<dim3(B_), dim3(512), 0, stream>>>(
            x, dl, m, xf, bz, br, bc, Bgh, Wgx, Bgx, PW, PG,
            pz, pr, pc, gm, c * CH);
        k2_mfma<<<dim3(B_ / 16), dim3(1024), 0, stream>>>(
            pz, pr, pc, gm, PU, hws);
    }
    k3_out<<<dim3(B_), dim3(O_), 0, stream>>>(hws, dW, db, bng, bnb, (float*)d_out);
}